// Round 11
// baseline (79.532 us; speedup 1.0000x reference)
//
#include <hip/hip_runtime.h>

// SelfAttention, C=1: q,k,v are scalar affines of x.
//   out_i = gamma*(wv*g(t_i)+bv) + x_i,  t_i=(wq*x_i+bq)*wk,
//   g(t) = sum_j x_j e^{t x_j} / sum_j e^{t x_j}   (log-partition derivative).
// g is analytic -> 64-node Chebyshev-Lobatto barycentric interp over the exact
// runtime t-range (error ~1e-20, superexponential convergence).
//
// FUSED single-launch version: 64 blocks = 8 per batch x 1024 threads.
// Each block stages x[b] (16 KB) in LDS, computes the full 64-node table
// itself (wave = 256-elem chunk, lane = node -> every LDS read is a
// same-address broadcast, conflict-free), reduces 16 chunk-partials per node
// through LDS, then evaluates its 512 rows barycentrically.
// No workspace, no second launch, no inter-kernel drain.

#define N_TOK   4096
#define NB      8
#define KN      64
#define BPB     8                 // row-blocks per batch
#define ROWS_PB (N_TOK / BPB)     // 512
#define NTHR    1024
#define NWAVE   (NTHR / 64)       // 16
#define CHUNK   (N_TOK / NWAVE)   // 256 elements summed per wave
#define LOG2E   1.4426950408889634f
#define PI_F    3.14159265358979323846f

__device__ __forceinline__ float fast_exp2(float v) { return __builtin_amdgcn_exp2f(v); }
__device__ __forceinline__ float fast_rcp(float v)  { return __builtin_amdgcn_rcpf(v); }

__global__ __launch_bounds__(NTHR) void SelfAttention_fused_kernel(
    const float* __restrict__ x,
    const float* __restrict__ pwq, const float* __restrict__ pbq,
    const float* __restrict__ pwk,
    const float* __restrict__ pwv, const float* __restrict__ pbv,
    const float* __restrict__ pgamma,
    float* __restrict__ out)
{
    __shared__ float  sx[N_TOK];        // 16 KB: x for this batch
    __shared__ float4 stab[KN];         // 1 KB : { t_k, w_k, w_k*g_k, 0 }
    __shared__ float  sred[2 * NWAVE];  // min/max partials
    __shared__ float  sS[NWAVE][KN];    // 4 KB : per-chunk denom partials
    __shared__ float  sW[NWAVE][KN];    // 4 KB : per-chunk numer partials

    const int tid  = threadIdx.x;
    const int lane = tid & 63;
    const int w    = tid >> 6;                 // wave 0..15
    const int b    = blockIdx.x >> 3;          // batch (BPB == 8)
    const int blk  = blockIdx.x & (BPB - 1);   // row-block within batch

    // issue scalar loads early; they resolve under the staging phase
    const float wq = *pwq, bq = *pbq, wk = *pwk;
    const float wv = *pwv, bv = *pbv, gamma = *pgamma;

    // ---- stage x[b] into LDS, block-wide exact min/max ----
    const float4* x4 = reinterpret_cast<const float4*>(x + b * N_TOK);
    const float4 v = x4[tid];                  // 1024 threads x 16 B = 16 KB
    reinterpret_cast<float4*>(sx)[tid] = v;
    float mx = fmaxf(fmaxf(v.x, v.y), fmaxf(v.z, v.w));
    float mn = fminf(fminf(v.x, v.y), fminf(v.z, v.w));
#pragma unroll
    for (int m = 32; m >= 1; m >>= 1) {
        mx = fmaxf(mx, __shfl_xor(mx, m, 64));
        mn = fminf(mn, __shfl_xor(mn, m, 64));
    }
    if (lane == 0) { sred[w] = mn; sred[NWAVE + w] = mx; }
    __syncthreads();
    mn = sred[0]; mx = sred[NWAVE];
#pragma unroll
    for (int q = 1; q < NWAVE; ++q) {
        mn = fminf(mn, sred[q]);
        mx = fmaxf(mx, sred[NWAVE + q]);
    }

    // ---- t-range (affine in x -> endpoints), slightly padded ----
    const float e1  = fmaf(wq, mn, bq) * wk;
    const float e2  = fmaf(wq, mx, bq) * wk;
    const float tlo = fminf(e1, e2), thi = fmaxf(e1, e2);
    const float cc  = 0.5f * (tlo + thi);
    const float rr  = 0.5f * (thi - tlo) * 1.0001f + 1e-7f;

    // ---- table phase: lane = node k, wave = chunk of 256 elements ----
    const float tk = cc + rr * cosf(PI_F * (float)lane / (float)(KN - 1));
    // stable shift: exact max of tk*x over [mn,mx] (node-global, chunk-safe)
    const float mshift = fmaxf(tk * mx, tk * mn);
    const float a = tk * LOG2E;
    const float c = mshift * LOG2E;

    float S = 0.f, W = 0.f;
    const float4* xs4 = reinterpret_cast<const float4*>(sx + w * CHUNK);
#pragma unroll 16
    for (int i = 0; i < CHUNK / 4; ++i) {
        const float4 u = xs4[i];               // same addr across wave: broadcast
        const float t0 = fast_exp2(fmaf(a, u.x, -c));
        const float t1 = fast_exp2(fmaf(a, u.y, -c));
        const float t2 = fast_exp2(fmaf(a, u.z, -c));
        const float t3 = fast_exp2(fmaf(a, u.w, -c));
        S += t0; W = fmaf(t0, u.x, W);
        S += t1; W = fmaf(t1, u.y, W);
        S += t2; W = fmaf(t2, u.z, W);
        S += t3; W = fmaf(t3, u.w, W);
    }
    sS[w][lane] = S;                           // stride-1 across lanes: conflict-free
    sW[w][lane] = W;
    __syncthreads();

    if (w == 0) {                              // 64 lanes finish 64 nodes
        float Ss = 0.f, Ws = 0.f;
#pragma unroll
        for (int q = 0; q < NWAVE; ++q) { Ss += sS[q][lane]; Ws += sW[q][lane]; }
        const float g = Ws / Ss;               // finite: global max term = 1 -> Ss >= 1
        float wgt = (lane == 0 || lane == KN - 1) ? 0.5f : 1.0f;
        if (lane & 1) wgt = -wgt;
        stab[lane] = make_float4(tk, wgt, wgt * g, 0.f);
    }
    __syncthreads();

    // ---- barycentric eval: this block's 512 rows, threads 0..511 ----
    if (tid < ROWS_PB) {
        const int   i  = blk * ROWS_PB + tid;
        const float xi = sx[i];
        const float t  = fmaf(wq, xi, bq) * wk;

        float num = 0.f, den = 0.f;
#pragma unroll 16
        for (int k = 0; k < KN; ++k) {
            const float4 e = stab[k];          // broadcast
            float d = t - e.x;
            d = copysignf(fmaxf(fabsf(d), 1e-12f), d);   // node-coincidence guard
            const float u = fast_rcp(d);
            num = fmaf(u, e.z, num);
            den = fmaf(u, e.y, den);
        }
        const float g = num * fast_rcp(den);
        const float o = fmaf(wv, g, bv);
        out[b * N_TOK + i] = fmaf(gamma, o, xi);
    }
}

extern "C" void kernel_launch(void* const* d_in, const int* in_sizes, int n_in,
                              void* d_out, int out_size, void* d_ws, size_t ws_size,
                              hipStream_t stream) {
    const float* x = (const float*)d_in[0];
    SelfAttention_fused_kernel<<<dim3(NB * BPB), dim3(NTHR), 0, stream>>>(
        x,
        (const float*)d_in[1], (const float*)d_in[2], (const float*)d_in[3],
        (const float*)d_in[5], (const float*)d_in[6], (const float*)d_in[7],
        (float*)d_out);
}

// Round 12
// 71.504 us; speedup vs baseline: 1.1123x; 1.1123x over previous
//
#include <hip/hip_runtime.h>

// SelfAttention, C=1: q,k,v are scalar affines of x.
//   out_i = gamma*(wv*g(t_i)+bv) + x_i,  t_i=(wq*x_i+bq)*wk,
//   g(t) = sum_j x_j e^{t x_j} / sum_j e^{t x_j}   (log-partition derivative).
// g is analytic -> 64-node Chebyshev-Lobatto barycentric interp over the exact
// runtime t-range (error ~1e-20, superexponential convergence).
// Phase A: exact g at 64 nodes/batch. One wave per (batch,node): x in VGPRs,
//          shfl_xor butterflies, no LDS, no syncthreads.
// Phase B: barycentric eval per row, one wave per 64 rows, table in LDS float4.
// NOTE (R11 post-mortem): fused single-launch variant measured 79.5 us vs
// this version's 70.7-72.5 us. The 268MB workspace poison-fill is unconditional
// (runs even when d_ws is unused), and the fused table redundancy ran on only
// 64 CUs. Two small spread-out launches win. Keeping proven structure.

#define N_TOK   4096
#define NB      8
#define KN      64
#define LOG2E   1.4426950408889634f
#define PI_F    3.14159265358979323846f

__device__ __forceinline__ float fast_exp2(float v) { return __builtin_amdgcn_exp2f(v); }
__device__ __forceinline__ float fast_rcp(float v)  { return __builtin_amdgcn_rcpf(v); }

// ---------------- Phase A: one wave per (batch, node) ----------------
__global__ __launch_bounds__(64) void SelfAttention_nodes_kernel(
    const float* __restrict__ x,
    const float* __restrict__ pwq, const float* __restrict__ pbq,
    const float* __restrict__ pwk,
    float4* __restrict__ tab)          // [NB][KN] = { t_k, w_k, w_k*g_k, 0 }
{
    const int lane = threadIdx.x;            // 0..63
    const int b    = blockIdx.x & (NB - 1);  // batch
    const int k    = blockIdx.x >> 3;        // node 0..KN-1

    // load 64 floats/lane into registers (16 x float4, coalesced)
    const float4* x4 = reinterpret_cast<const float4*>(x + b * N_TOK);
    float4 v[16];
    float mx = -__builtin_inff(), mn = __builtin_inff();
#pragma unroll
    for (int q = 0; q < 16; ++q) {
        v[q] = x4[lane + q * 64];
        mx = fmaxf(mx, fmaxf(fmaxf(v[q].x, v[q].y), fmaxf(v[q].z, v[q].w)));
        mn = fminf(mn, fminf(fminf(v[q].x, v[q].y), fminf(v[q].z, v[q].w)));
    }
    // butterfly: every lane ends with the global min/max (exactly associative)
#pragma unroll
    for (int m = 32; m >= 1; m >>= 1) {
        mx = fmaxf(mx, __shfl_xor(mx, m, 64));
        mn = fminf(mn, __shfl_xor(mn, m, 64));
    }

    const float wq = *pwq, bq = *pbq, wk = *pwk;

    // t-range (affine in x -> endpoints), slightly padded
    const float e1  = fmaf(wq, mn, bq) * wk;
    const float e2  = fmaf(wq, mx, bq) * wk;
    const float tlo = fminf(e1, e2), thi = fmaxf(e1, e2);
    const float cc  = 0.5f * (tlo + thi);
    const float rr  = 0.5f * (thi - tlo) * 1.0001f + 1e-7f;

    const float tk = cc + rr * cosf(PI_F * (float)k / (float)(KN - 1));

    // stable shift: exact max of tk*x over [mn,mx]
    const float mshift = fmaxf(tk * mx, tk * mn);
    const float a = tk * LOG2E;
    const float c = mshift * LOG2E;

    float S = 0.f, W = 0.f;
#pragma unroll
    for (int q = 0; q < 16; ++q) {
        float t0 = fast_exp2(fmaf(a, v[q].x, -c));
        float t1 = fast_exp2(fmaf(a, v[q].y, -c));
        float t2 = fast_exp2(fmaf(a, v[q].z, -c));
        float t3 = fast_exp2(fmaf(a, v[q].w, -c));
        S += t0; W = fmaf(t0, v[q].x, W);
        S += t1; W = fmaf(t1, v[q].y, W);
        S += t2; W = fmaf(t2, v[q].z, W);
        S += t3; W = fmaf(t3, v[q].w, W);
    }
#pragma unroll
    for (int m = 32; m >= 1; m >>= 1) {
        S += __shfl_xor(S, m, 64);
        W += __shfl_xor(W, m, 64);
    }

    if (lane == 0) {
        const float g = W / S;                       // finite: S >= 1 (max term = 1)
        float wgt = (k == 0 || k == KN - 1) ? 0.5f : 1.0f;
        if (k & 1) wgt = -wgt;
        tab[b * KN + k] = make_float4(tk, wgt, wgt * g, 0.f);
    }
}

// ---------------- Phase B: one wave per 64 rows ----------------
__global__ __launch_bounds__(64) void SelfAttention_rows_kernel(
    const float* __restrict__ x,
    const float* __restrict__ pwq, const float* __restrict__ pbq,
    const float* __restrict__ pwk,
    const float* __restrict__ pwv, const float* __restrict__ pbv,
    const float* __restrict__ pgamma,
    const float4* __restrict__ tab,
    float* __restrict__ out)
{
    __shared__ float4 stab[KN];

    const int lane = threadIdx.x;
    const int b    = blockIdx.x & (NB - 1);
    const int blk  = blockIdx.x >> 3;        // 0..63

    stab[lane] = tab[b * KN + lane];         // 64 lanes load 64 entries
    __syncthreads();

    const float wq = *pwq, bq = *pbq, wk = *pwk;
    const float wv = *pwv, bv = *pbv, gamma = *pgamma;

    const int   i  = blk * 64 + lane;
    const float xi = x[b * N_TOK + i];
    const float t  = fmaf(wq, xi, bq) * wk;

    float num = 0.f, den = 0.f;
#pragma unroll 16
    for (int k = 0; k < KN; ++k) {
        const float4 e = stab[k];            // same addr across wave: broadcast
        float d = t - e.x;
        d = copysignf(fmaxf(fabsf(d), 1e-12f), d);   // node-coincidence guard
        const float u = fast_rcp(d);
        num = fmaf(u, e.z, num);
        den = fmaf(u, e.y, den);
    }
    const float g = num * fast_rcp(den);
    const float o = fmaf(wv, g, bv);
    out[b * N_TOK + i] = fmaf(gamma, o, xi);
}

extern "C" void kernel_launch(void* const* d_in, const int* in_sizes, int n_in,
                              void* d_out, int out_size, void* d_ws, size_t ws_size,
                              hipStream_t stream) {
    const float* x = (const float*)d_in[0];
    float4* tab = (float4*)d_ws;   // NB*KN*16 B = 8 KB

    SelfAttention_nodes_kernel<<<dim3(NB * KN), dim3(64), 0, stream>>>(
        x, (const float*)d_in[1], (const float*)d_in[2], (const float*)d_in[3], tab);

    SelfAttention_rows_kernel<<<dim3(NB * (N_TOK / 64)), dim3(64), 0, stream>>>(
        x, (const float*)d_in[1], (const float*)d_in[2], (const float*)d_in[3],
        (const float*)d_in[5], (const float*)d_in[6], (const float*)d_in[7],
        tab, (float*)d_out);
}